// Round 17
// baseline (286.661 us; speedup 1.0000x reference)
//
#include <hip/hip_runtime.h>
#include <stdint.h>

typedef unsigned short u16;
typedef __attribute__((ext_vector_type(8))) short short8;
typedef __attribute__((ext_vector_type(4))) float f32x4;

#define M_DIM 8192
#define N_DIM 4096
#define K_DIM 4096

// ---------- fused fp32 -> bf16 (RNE) for x and w in one launch ----------
__device__ inline u16 f32_to_bf16_rne(float f) {
    uint32_t b = __builtin_bit_cast(uint32_t, f);
    b += 0x7fffu + ((b >> 16) & 1u);
    return (u16)(b >> 16);
}

__global__ __launch_bounds__(256)
void cvt_both_k(const float* __restrict__ x, u16* __restrict__ xb, int nx_vec8,
                const float* __restrict__ w, u16* __restrict__ wb, int nw_vec8) {
    const int total = nx_vec8 + nw_vec8;
    const int stride = gridDim.x * blockDim.x;
    for (int i = blockIdx.x * blockDim.x + threadIdx.x; i < total; i += stride) {
        const float* in;
        u16* out;
        int idx;
        if (i < nx_vec8) { in = x; out = xb; idx = i; }
        else             { in = w; out = wb; idx = i - nx_vec8; }
        const float4* p = reinterpret_cast<const float4*>(in) + 2 * (size_t)idx;
        float4 a = p[0];
        float4 b = p[1];
        float v[8] = {a.x, a.y, a.z, a.w, b.x, b.y, b.z, b.w};
        short8 r;
#pragma unroll
        for (int j = 0; j < 8; ++j) r[j] = (short)f32_to_bf16_rne(v[j]);
        *reinterpret_cast<short8*>(out + 8 * (size_t)idx) = r;
    }
}

// ---------- 256x256 bf16 GEMM: BK=32, 4-buffer rotation, 1 barrier/body ----------
// A: [M][K] bf16, B: [N][K] bf16 (B^T), C: [M][N] f32
// 512 threads = 8 waves (2M x 4N); per-wave output 128x64; BK=32 per body.
// LDS: 4 buffers x {A 256x32, B 256x32} bf16 = 4 x 32 KiB = 128 KiB.
// Rows are 64 B. Swizzle = r14-HW-validated scheme (0 conflicts, refcheck'd):
//   DMA chunk map: physical cp holds logical cl = (cp&~3)|((cp&3)^((cp>>3)&3))
//   read: key=((lane&15)>>1)&3, cpos=((lane>>4)<<4)^(key<<4)
//
// Body t (buf bt=t&3, next bn=(t+1)&3), 2 phases of 16 MFMA:
//   VM(4)  outstanding = {staged@t-2: tile t+1, staged@t-1: tile t+2} = 8
//          -> drains tile t+1 (issued 2 bodies ~2.5k cyc ago >> 900 HBM: no stall)
//   BAR    publishes tile t+1 (the ONLY barrier per body)
//   ph1: rd aM1<-bt.A.mh1 (4) + bNxt[0..1]<-bn.B (2) | STAGE tile t+3 (4 DMA)
//        LGKM(6) (drains prev ph2's 6) | MFMA16(aM0, bCur, mh0)
//   ph2: rd aM0<-bn.A.mh0 (4) + bNxt[2..3]<-bn.B (2)
//        LGKM(6) (drains ph1's 6)      | MFMA16(aM1, bCur, mh1)
// Uniform 6 reads/phase (CU drain 576 cyc < MFMA 620). Stage-WAR: buf[t-1]'s
// last reads drained at body t-1 ph2 LGKM, all waves pass body-t BAR after
// that -> STAGE@body t+? targeting buf[t-1] ((t+3)&3=(t-1)&3) is safe.
// Reg WAR: aM0 w@ph2 use@next-ph1; aM1 w@ph1 use@ph2; bX/bY alternate by
// body parity (w@t, use@t+1, rewrite@t+2). Tail: wrapped stages/reads hit
// valid (k=0) data, results discarded; drained by final VM0/LGKM0.

#define BAR() do { asm volatile("" ::: "memory"); __builtin_amdgcn_s_barrier(); asm volatile("" ::: "memory"); } while (0)
#define LGKM(n) do { asm volatile("s_waitcnt lgkmcnt(" #n ")" ::: "memory"); __builtin_amdgcn_sched_barrier(0); } while (0)
#define WAIT_VM8() asm volatile("s_waitcnt vmcnt(8)" ::: "memory")
#define WAIT_VM4() asm volatile("s_waitcnt vmcnt(4)" ::: "memory")
#define WAIT_VM0() asm volatile("s_waitcnt vmcnt(0)" ::: "memory")

// 16 MFMA: 4 m-frags x 4 n-frags at one mh
#define MFMA16(AA, BB, MH)                                                        \
    _Pragma("unroll")                                                             \
    for (int m = 0; m < 4; ++m) {                                                 \
        _Pragma("unroll")                                                         \
        for (int n = 0; n < 4; ++n) {                                             \
            acc[(MH) * 4 + m][n] =                                                \
                __builtin_amdgcn_mfma_f32_16x16x32_bf16(                          \
                    AA[m], BB[n], acc[(MH) * 4 + m][n], 0, 0, 0);                 \
        }                                                                         \
    }

#define READ_A4(AA, P, MHOFF)                                                     \
    _Pragma("unroll")                                                             \
    for (int m = 0; m < 4; ++m) {                                                 \
        AA[m] = *reinterpret_cast<const short8*>((P) + (MHOFF) + m * 1024);       \
    }

// one body: tiles t (buf BT) mh0+mh1; prefetch operand tile t+1 (buf BN);
// stage tile t+3 into buf BS at k-offset KS; BCUR consumed, BNXT written.
#define BODY(BT, BN, BS, KS, BCUR, BNXT)                                          \
    WAIT_VM4();                                                                   \
    BAR();                                                                        \
    READ_A4(aM1, pA[BT], 4096);                                                   \
    BNXT[0] = *reinterpret_cast<const short8*>(pB[BN]);                           \
    BNXT[1] = *reinterpret_cast<const short8*>(pB[BN] + 1024);                    \
    STAGE(BS, KS);                                                                \
    LGKM(6);                                                                      \
    __builtin_amdgcn_s_setprio(1);                                                \
    MFMA16(aM0, BCUR, 0);                                                         \
    __builtin_amdgcn_s_setprio(0);                                                \
    READ_A4(aM0, pA[BN], 0);                                                      \
    BNXT[2] = *reinterpret_cast<const short8*>(pB[BN] + 2048);                    \
    BNXT[3] = *reinterpret_cast<const short8*>(pB[BN] + 3072);                    \
    LGKM(6);                                                                      \
    __builtin_amdgcn_s_setprio(1);                                                \
    MFMA16(aM1, BCUR, 1);                                                         \
    __builtin_amdgcn_s_setprio(0);

__global__ __launch_bounds__(512, 2)
void gemm_bk32(const u16* __restrict__ A, const u16* __restrict__ B,
               const float* __restrict__ bias, float* __restrict__ C) {
    // buf b: A = [0..8191] (256x32), B = [8192..16383] (256x32)
    __shared__ __align__(16) u16 lds[4][16384];   // 128 KiB

    const int tid  = threadIdx.x;
    const int wave = tid >> 6;
    const int lane = tid & 63;

    // T1: XCD-aware bijective swizzle (nwg=512, 512%8==0)
    const uint32_t wg = (blockIdx.x & 7u) * 64u + (blockIdx.x >> 3);
    const int bx = (int)(wg % (N_DIM / 256));
    const int by = (int)(wg / (N_DIM / 256));
    const int brow = by * 256;
    const int bcol = bx * 256;

    const int wr = wave >> 2;   // 0..1 -> 128 output rows
    const int wc = wave & 3;    // 0..3 -> 64 output cols

    // DMA source maps: A/B regions each 256x32 = 1024 chunks; 2 chunks/thread
    uint32_t rS[2], cS[2];
#pragma unroll
    for (int j = 0; j < 2; ++j) {
        const uint32_t cp = (uint32_t)tid + 512u * j;
        const uint32_t cl = (cp & ~3u) | ((cp & 3u) ^ ((cp >> 3) & 3u));
        rS[j] = cl >> 2;           // row 0..255
        cS[j] = (cl & 3u) * 8u;    // col in u16
    }

    const u16* gA = A + (size_t)brow * K_DIM;
    const u16* gB = B + (size_t)bcol * K_DIM;

    auto STAGE = [&](int b, int k0) {
        u16* la = &lds[b][0];
        u16* lb = &lds[b][8192];
#pragma unroll
        for (int j = 0; j < 2; ++j) {
            __builtin_amdgcn_global_load_lds(
                (const __attribute__((address_space(1))) uint32_t*)(gA + (size_t)rS[j] * K_DIM + k0 + cS[j]),
                (__attribute__((address_space(3))) uint32_t*)(la + wave * 512 + j * 4096), 16, 0, 0);
        }
#pragma unroll
        for (int j = 0; j < 2; ++j) {
            __builtin_amdgcn_global_load_lds(
                (const __attribute__((address_space(1))) uint32_t*)(gB + (size_t)rS[j] * K_DIM + k0 + cS[j]),
                (__attribute__((address_space(3))) uint32_t*)(lb + wave * 512 + j * 4096), 16, 0, 0);
        }
    };

    // per-lane swizzled read bases per buffer (r14-validated 64B-row scheme)
    const uint32_t key  = (((uint32_t)lane & 15u) >> 1) & 3u;
    const uint32_t cpos = (((uint32_t)lane >> 4) << 4) ^ (key << 4);
    const uint32_t arow = ((uint32_t)wr * 128u + ((uint32_t)lane & 15u)) * 64u;
    const uint32_t brw  = ((uint32_t)wc * 64u  + ((uint32_t)lane & 15u)) * 64u;

    const char* pA[4];
    const char* pB[4];
#pragma unroll
    for (int b = 0; b < 4; ++b) {
        pA[b] = (const char*)&lds[b][0]    + arow + cpos;
        pB[b] = (const char*)&lds[b][8192] + brw  + cpos;
    }

    f32x4 acc[8][4];
#pragma unroll
    for (int m = 0; m < 8; ++m)
#pragma unroll
        for (int n = 0; n < 4; ++n) acc[m][n] = (f32x4){0.f, 0.f, 0.f, 0.f};

    short8 aM0[4], aM1[4], bX[4], bY[4];

    // ---- prologue: stage tiles 0,1,2; VM(8) drains tile 0; pre-read
    //      aM0 <- A(0).mh0, bX <- B(0) (8 reads) ----
    STAGE(0, 0);
    STAGE(1, 32);
    STAGE(2, 64);
    WAIT_VM8();
    BAR();
    READ_A4(aM0, pA[0], 0);
#pragma unroll
    for (int n = 0; n < 4; ++n)
        bX[n] = *reinterpret_cast<const short8*>(pB[0] + n * 1024);

    // ---- main loop: 32 iters x 4 bodies; t = 4i+j, buf = j ----
    for (int i = 0; i < K_DIM / 128; ++i) {
        const int t0 = 4 * i;
        // body j=0: t even -> consume bX, write bY; stage tile t0+3 -> buf3
        BODY(0, 1, 3, ((t0 + 3) * 32) & (K_DIM - 1), bX, bY)
        // body j=1: odd -> consume bY, write bX; stage t0+4 -> buf0
        BODY(1, 2, 0, ((t0 + 4) * 32) & (K_DIM - 1), bY, bX)
        // body j=2: even -> consume bX, write bY; stage t0+5 -> buf1
        BODY(2, 3, 1, ((t0 + 5) * 32) & (K_DIM - 1), bX, bY)
        // body j=3: odd -> consume bY, write bX; stage t0+6 -> buf2
        BODY(3, 0, 2, ((t0 + 6) * 32) & (K_DIM - 1), bY, bX)
    }

    WAIT_VM0();    // drain wrapped prefetches
    LGKM(0);       // drain dangling tail reads before epilogue reuses regs

    // ---- epilogue: C/D layout col=lane&15, row=(lane>>4)*4+j ----
    const int orow = brow + wr * 128 + (lane >> 4) * 4;
    const int ocol = bcol + wc * 64 + (lane & 15);
#pragma unroll
    for (int n = 0; n < 4; ++n) {
        const int c = ocol + n * 16;
        const float bv = bias[c];
#pragma unroll
        for (int m = 0; m < 8; ++m) {
#pragma unroll
            for (int j = 0; j < 4; ++j) {
                C[(size_t)(orow + m * 16 + j) * N_DIM + c] = acc[m][n][j] + bv;
            }
        }
    }
}

// ---------- fallback (ws too small): correct, slow fp32 ----------
__global__ __launch_bounds__(256)
void gemm_f32_naive(const float* __restrict__ x, const float* __restrict__ w,
                    const float* __restrict__ bias, float* __restrict__ out) {
    const size_t total = (size_t)M_DIM * N_DIM;
    const size_t stride = (size_t)gridDim.x * blockDim.x;
    for (size_t idx = (size_t)blockIdx.x * blockDim.x + threadIdx.x; idx < total; idx += stride) {
        const int b = (int)(idx / N_DIM);
        const int o = (int)(idx % N_DIM);
        const float* xr = x + (size_t)b * K_DIM;
        const float* wr = w + (size_t)o * K_DIM;
        float s = bias[o];
        for (int k = 0; k < K_DIM; ++k) s = fmaf(xr[k], wr[k], s);
        out[idx] = s;
    }
}

extern "C" void kernel_launch(void* const* d_in, const int* in_sizes, int n_in,
                              void* d_out, int out_size, void* d_ws, size_t ws_size,
                              hipStream_t stream) {
    const float* x    = (const float*)d_in[0];
    const float* w    = (const float*)d_in[1];
    const float* bias = (const float*)d_in[2];
    float* out = (float*)d_out;

    const size_t xb_elems = (size_t)M_DIM * K_DIM;
    const size_t wb_elems = (size_t)N_DIM * K_DIM;
    const size_t need = (xb_elems + wb_elems) * sizeof(u16);

    if (ws_size >= need) {
        u16* xb = (u16*)d_ws;
        u16* wb = xb + xb_elems;
        cvt_both_k<<<2048, 256, 0, stream>>>(x, xb, (int)(xb_elems / 8),
                                             w, wb, (int)(wb_elems / 8));
        const int nwg = (M_DIM / 256) * (N_DIM / 256);   // 32*16 = 512
        gemm_bk32<<<nwg, 512, 0, stream>>>(xb, wb, bias, out);
    } else {
        gemm_f32_naive<<<4096, 256, 0, stream>>>(x, w, bias, out);
    }
}